// Round 5
// baseline (875.806 us; speedup 1.0000x reference)
//
#include <hip/hip_runtime.h>
#include <hip/hip_bf16.h>

typedef float  f32x4 __attribute__((ext_vector_type(4)));
typedef short  s16x8 __attribute__((ext_vector_type(8)));
typedef short  s16x4 __attribute__((ext_vector_type(4)));

#define NEGBIG -1e30f

__device__ __forceinline__ unsigned short f2b(float f) {
    union { float f; unsigned u; } c; c.f = f;
    unsigned r = c.u + 0x7FFF + ((c.u >> 16) & 1);
    return (unsigned short)(r >> 16);
}
__device__ __forceinline__ float b2f(unsigned short h) {
    union { unsigned u; float f; } c; c.u = ((unsigned)h) << 16;
    return c.f;
}
__device__ __forceinline__ float sigm(float x) { return 1.f / (1.f + __expf(-x)); }

// coherent (agent-scope) accessors: bypass per-XCD L1/L2, hit the memory-side coherence point.
__device__ __forceinline__ s16x8 ld_b128_sc(const unsigned short* p) {
    s16x8 r;
    asm volatile("global_load_dwordx4 %0, %1, off sc0 sc1" : "=v"(r) : "v"(p));
    return r;
}
__device__ __forceinline__ void st_b64_sc(unsigned short* p, unsigned int x, unsigned int y) {
    union { unsigned int u[2]; unsigned long long ull; } v; v.u[0] = x; v.u[1] = y;
    asm volatile("global_store_dwordx2 %0, %1, off sc0 sc1" :: "v"(p), "v"(v.ull) : "memory");
}

// Poll 16 h-chunks (16B each, stride 32 shorts) until no granule is poison.
// Each 8B granule is written by ONE dwordx2 store => checking elems 0 and 4 suffices.
// Retries re-issue only failed chunks, with s_sleep backoff (r3 lesson: no backoff = L3 congestion).
#define POLL_H(BASE, AF) do {                                                        \
    unsigned okm_ = 0; int guard_ = 0;                                               \
    while (true) {                                                                   \
        _Pragma("unroll")                                                            \
        for (int kk_ = 0; kk_ < 16; ++kk_)                                           \
            if (!((okm_ >> kk_) & 1)) AF[kk_] = ld_b128_sc((BASE) + kk_ * 32);       \
        asm volatile("s_waitcnt vmcnt(0)" ::: "memory");                             \
        __builtin_amdgcn_sched_barrier(0);                                           \
        _Pragma("unroll")                                                            \
        for (int kk_ = 0; kk_ < 16; ++kk_) if (!((okm_ >> kk_) & 1)) {               \
            bool ok_ = ((unsigned short)AF[kk_][0] != (unsigned short)0xFFFFu)       \
                    && ((unsigned short)AF[kk_][4] != (unsigned short)0xFFFFu);      \
            if (ok_) okm_ |= (1u << kk_);                                            \
        }                                                                            \
        if (__all(okm_ == 0xFFFFu)) break;                                           \
        if (++guard_ > (1 << 18)) break;  /* safety: no hang */                      \
        __builtin_amdgcn_s_sleep(1);                                                 \
    }                                                                                \
    __builtin_amdgcn_sched_barrier(0);                                               \
} while (0)

// ---------------------------------------------------------------- init
__global__ void init_zero(unsigned short* hb0, unsigned short* hb1, unsigned short* hb2, unsigned short* hb3) {
    int idx = blockIdx.x * 256 + threadIdx.x;
    int stride = gridDim.x * 256;
    for (int i = idx; i < 32768; i += stride) {
        hb0[i] = 0;               // h_0 = 0 (valid data: passes poison check immediately)
        hb1[i] = 0xFFFFu;         // poison
        hb2[i] = 0xFFFFu;         // poison
        hb3[i] = 0xFFFFu;         // poison
    }
}

// ---------------------------------------------------------------- prep weights (bf16 casts + Wqkv concat-transpose)
__global__ void prep_w(const float* Wq, const float* Wk, const float* Wv,
                       const float* gWih, const float* gWhh,
                       unsigned short* wcat, unsigned short* wih, unsigned short* whh) {
    int idx = blockIdx.x * 256 + threadIdx.x;
    int stride = gridDim.x * 256;
    const int N1 = 131072, N2 = 491520, N3 = 786432;
    for (; idx < N1 + N2 + N3; idx += stride) {
        if (idx < N1) {
            int n = idx >> 8, k = idx & 255;
            float v;
            if (n < 128) v = Wq[k * 128 + n];
            else if (n < 256) v = Wk[k * 128 + (n - 128)];
            else v = Wv[k * 256 + (n - 256)];
            wcat[n * 256 + k] = f2b(v);
        } else if (idx < N1 + N2) {
            int i = idx - N1; wih[i] = f2b(gWih[i]);
        } else {
            int i = idx - N1 - N2; whh[i] = f2b(gWhh[i]);
        }
    }
}

// ---------------------------------------------------------------- prep E^T  [256][4096] bf16
__global__ __launch_bounds__(256) void prep_et(const float* code_emb, const int* ct0, const int* ct1, const int* ct2,
                                               const float* t0e, const float* t1e, const float* t2e,
                                               unsigned short* ET) {
    __shared__ float tile[64][65];
    const int d0 = blockIdx.x * 64, c0 = blockIdx.y * 64;
    const int t = threadIdx.x;
    for (int p = 0; p < 16; ++p) {
        int idx = p * 256 + t;
        int dl = idx & 63, cl = idx >> 6;   // cl in [0,64) over passes
        int code = c0 + cl + 1;
        int d = d0 + dl;
        float v = code_emb[code * 256 + d] + t0e[ct0[code] * 256 + d]
                + t1e[ct1[code] * 256 + d] + t2e[ct2[code] * 256 + d];
        tile[dl][cl] = v;
    }
    __syncthreads();
    for (int p = 0; p < 2; ++p) {
        int idx = p * 256 + t;
        int dl = idx >> 3, ch = idx & 7;
        s16x8 pk;
#pragma unroll
        for (int e = 0; e < 8; ++e) pk[e] = (short)f2b(tile[dl][ch * 8 + e]);
        *(s16x8*)(ET + (size_t)(d0 + dl) * 4096 + c0 + ch * 8) = pk;
    }
}

// ---------------------------------------------------------------- encoder GEMM: v = mask*( (code_x>0) @ E ) / counts
__global__ __launch_bounds__(256) void enc_gemm(const float* code_x, const unsigned short* ET,
                                                const int* lens, unsigned short* Vb) {
    __shared__ __align__(16) char sm[4096 + 32768 + 128];
    char* As = sm;
    char* Bs = sm + 4096;
    float* cl = (float*)(sm + 4096 + 32768);
    const int m0 = blockIdx.x * 32;
    const int t = threadIdx.x, l = t & 63, w = t >> 6;
    const int lr = l & 15, lq = l >> 4, l7 = l & 7;
    const int sr = t >> 3, sc = t & 7;
    f32x4 acc[2][4];
#pragma unroll
    for (int a = 0; a < 2; ++a)
#pragma unroll
        for (int b = 0; b < 4; ++b) acc[a][b] = (f32x4){0.f, 0.f, 0.f, 0.f};
    int cnt = 0;
    for (int it = 0; it < 64; ++it) {
        const int k0 = it * 64;
        const float* ga = code_x + (size_t)(m0 + sr) * 4096 + k0 + sc * 8;
        f32x4 a0 = *(const f32x4*)ga;
        f32x4 a1 = *(const f32x4*)(ga + 4);
        s16x8 ap;
#pragma unroll
        for (int e = 0; e < 4; ++e) { bool on = a0[e] > 0.f; ap[e] = on ? (short)0x3F80 : (short)0; cnt += on ? 1 : 0; }
#pragma unroll
        for (int e = 0; e < 4; ++e) { bool on = a1[e] > 0.f; ap[4 + e] = on ? (short)0x3F80 : (short)0; cnt += on ? 1 : 0; }
        *(s16x8*)(As + sr * 128 + ((sc ^ (sr & 7)) << 4)) = ap;
#pragma unroll
        for (int rd = 0; rd < 8; ++rd) {
            int i = rd * 256 + t;
            int n = i >> 3, cc = i & 7;
            s16x8 bv = *(const s16x8*)(ET + (size_t)n * 4096 + k0 + cc * 8);
            *(s16x8*)(Bs + n * 128 + ((cc ^ (n & 7)) << 4)) = bv;
        }
        __syncthreads();
#pragma unroll
        for (int kk = 0; kk < 2; ++kk) {
            const int cp = kk * 4 + lq;
            s16x8 af[2], bf[4];
#pragma unroll
            for (int mt = 0; mt < 2; ++mt)
                af[mt] = *(const s16x8*)(As + (mt * 16 + lr) * 128 + ((cp ^ l7) << 4));
#pragma unroll
            for (int nt = 0; nt < 4; ++nt)
                bf[nt] = *(const s16x8*)(Bs + ((w * 4 + nt) * 16 + lr) * 128 + ((cp ^ l7) << 4));
#pragma unroll
            for (int mt = 0; mt < 2; ++mt)
#pragma unroll
                for (int nt = 0; nt < 4; ++nt)
                    acc[mt][nt] = __builtin_amdgcn_mfma_f32_16x16x32_bf16(af[mt], bf[nt], acc[mt][nt], 0, 0, 0);
        }
        __syncthreads();
    }
    float fc = (float)cnt;
    fc += __shfl_xor(fc, 1); fc += __shfl_xor(fc, 2); fc += __shfl_xor(fc, 4);
    if (sc == 0) cl[sr] = fmaxf(fc, 1.f);
    __syncthreads();
#pragma unroll
    for (int mt = 0; mt < 2; ++mt)
#pragma unroll
        for (int i = 0; i < 4; ++i) {
            int m = mt * 16 + lq * 4 + i;
            int gm = m0 + m;
            float rc = 1.f / cl[m];
            unsigned bi = (unsigned)gm / 100u;
            unsigned vi = (unsigned)gm - bi * 100u;
            float msk = ((int)vi < lens[bi]) ? 1.f : 0.f;
#pragma unroll
            for (int nt = 0; nt < 4; ++nt) {
                int n = (w * 4 + nt) * 16 + lr;
                Vb[(size_t)gm * 256 + n] = f2b(acc[mt][nt][i] * rc * msk);
            }
        }
}

// ---------------------------------------------------------------- generic bf16 GEMM (A[M][K] @ B[N][K]^T), M tiled by 32, N by 256
// mode 1: out bf16 plain + bias; mode 2: out bf16 plain, no bias
__global__ __launch_bounds__(256) void gemm_bf16(const unsigned short* A, const unsigned short* Bm,
                                                 int K, int Ntot, int mode,
                                                 unsigned short* outp, const float* bias) {
    __shared__ __align__(16) char sm[4096 + 32768];
    char* As = sm;
    char* Bs = sm + 4096;
    const int m0 = blockIdx.x * 32;
    const int n0 = blockIdx.y * 256;
    const int t = threadIdx.x, l = t & 63, w = t >> 6;
    const int lr = l & 15, lq = l >> 4, l7 = l & 7;
    const int sr = t >> 3, sc = t & 7;
    const int iters = K >> 6;
    f32x4 acc[2][4];
#pragma unroll
    for (int a = 0; a < 2; ++a)
#pragma unroll
        for (int b = 0; b < 4; ++b) acc[a][b] = (f32x4){0.f, 0.f, 0.f, 0.f};
    for (int it = 0; it < iters; ++it) {
        const int k0 = it * 64;
        s16x8 av = *(const s16x8*)(A + (size_t)(m0 + sr) * K + k0 + sc * 8);
        *(s16x8*)(As + sr * 128 + ((sc ^ (sr & 7)) << 4)) = av;
#pragma unroll
        for (int rd = 0; rd < 8; ++rd) {
            int i = rd * 256 + t;
            int n = i >> 3, cc = i & 7;
            s16x8 bv = *(const s16x8*)(Bm + (size_t)(n0 + n) * K + k0 + cc * 8);
            *(s16x8*)(Bs + n * 128 + ((cc ^ (n & 7)) << 4)) = bv;
        }
        __syncthreads();
#pragma unroll
        for (int kk = 0; kk < 2; ++kk) {
            const int cp = kk * 4 + lq;
            s16x8 af[2], bf[4];
#pragma unroll
            for (int mt = 0; mt < 2; ++mt)
                af[mt] = *(const s16x8*)(As + (mt * 16 + lr) * 128 + ((cp ^ l7) << 4));
#pragma unroll
            for (int nt = 0; nt < 4; ++nt)
                bf[nt] = *(const s16x8*)(Bs + ((w * 4 + nt) * 16 + lr) * 128 + ((cp ^ l7) << 4));
#pragma unroll
            for (int mt = 0; mt < 2; ++mt)
#pragma unroll
                for (int nt = 0; nt < 4; ++nt)
                    acc[mt][nt] = __builtin_amdgcn_mfma_f32_16x16x32_bf16(af[mt], bf[nt], acc[mt][nt], 0, 0, 0);
        }
        __syncthreads();
    }
#pragma unroll
    for (int mt = 0; mt < 2; ++mt)
#pragma unroll
        for (int i = 0; i < 4; ++i) {
            int gm = m0 + mt * 16 + lq * 4 + i;
#pragma unroll
            for (int nt = 0; nt < 4; ++nt) {
                int n = n0 + (w * 4 + nt) * 16 + lr;
                float v = acc[mt][nt][i];
                if (mode == 1) v += bias[n];
                outp[(size_t)gm * Ntot + n] = f2b(v);
            }
        }
}

// ---------------------------------------------------------------- attention (one block per batch) + time-emb concat
__global__ __launch_bounds__(256) void attn_kernel(const unsigned short* QKV, const int* lens,
                                                   const float* intervals, const float* time_w, const float* time_b,
                                                   unsigned short* X) {
    __shared__ __align__(16) char sm[28672 + 32768];
    char* Pb = sm;            // P: 112 rows x 128 cols bf16, pitch 256B, swizzled
    char* VTb = sm + 28672;   // V^T half: 128 d x 128 j bf16, pitch 256B, swizzled
    const int b = blockIdx.x;
    const int t = threadIdx.x, l = t & 63, w = t >> 6;
    const int lr = l & 15, lq = l >> 4;
    const int lenb = lens[b];
    // zero P
    for (int p = 0; p < 7; ++p) {
        int idx = p * 256 + t;
        *(f32x4*)(Pb + idx * 16) = (f32x4){0.f, 0.f, 0.f, 0.f};
    }
    __syncthreads();
    // ---- S = Q K^T  (rows 2w..2w+1 tiles of 16; wave 3 handles tile 6 only)
    f32x4 S[2][7];
#pragma unroll
    for (int a = 0; a < 2; ++a)
#pragma unroll
        for (int c = 0; c < 7; ++c) S[a][c] = (f32x4){0.f, 0.f, 0.f, 0.f};
#pragma unroll
    for (int kk = 0; kk < 4; ++kk) {
        s16x8 qa[2], kb[7];
#pragma unroll
        for (int mi = 0; mi < 2; ++mi) {
            int mt = 2 * w + mi;
            if (mt > 6) continue;
            int row = b * 100 + mt * 16 + lr;
            qa[mi] = *(const s16x8*)(QKV + (size_t)row * 512 + kk * 32 + lq * 8);
        }
#pragma unroll
        for (int nt = 0; nt < 7; ++nt) {
            int row = b * 100 + nt * 16 + lr;
            kb[nt] = *(const s16x8*)(QKV + (size_t)row * 512 + 128 + kk * 32 + lq * 8);
        }
#pragma unroll
        for (int mi = 0; mi < 2; ++mi) {
            int mt = 2 * w + mi;
            if (mt > 6) continue;
#pragma unroll
            for (int nt = 0; nt < 7; ++nt)
                S[mi][nt] = __builtin_amdgcn_mfma_f32_16x16x32_bf16(qa[mi], kb[nt], S[mi][nt], 0, 0, 0);
        }
    }
    // ---- softmax rows (all in shuffle groups of 16), store P to LDS
#pragma unroll
    for (int mi = 0; mi < 2; ++mi) {
        int mt = 2 * w + mi;
        if (mt > 6) continue;
        float sv[7][4];
#pragma unroll
        for (int nt = 0; nt < 7; ++nt) {
            int j = nt * 16 + lr;
#pragma unroll
            for (int i = 0; i < 4; ++i)
                sv[nt][i] = (j < lenb) ? S[mi][nt][i] : NEGBIG;
        }
#pragma unroll
        for (int i = 0; i < 4; ++i) {
            float mx = sv[0][i];
#pragma unroll
            for (int nt = 1; nt < 7; ++nt) mx = fmaxf(mx, sv[nt][i]);
            mx = fmaxf(mx, __shfl_xor(mx, 1));
            mx = fmaxf(mx, __shfl_xor(mx, 2));
            mx = fmaxf(mx, __shfl_xor(mx, 4));
            mx = fmaxf(mx, __shfl_xor(mx, 8));
            float e[7], sum = 0.f;
#pragma unroll
            for (int nt = 0; nt < 7; ++nt) { e[nt] = __expf(sv[nt][i] - mx); sum += e[nt]; }
            sum += __shfl_xor(sum, 1);
            sum += __shfl_xor(sum, 2);
            sum += __shfl_xor(sum, 4);
            sum += __shfl_xor(sum, 8);
            float rs = 1.f / sum;
            int m = mt * 16 + lq * 4 + i;
#pragma unroll
            for (int nt = 0; nt < 7; ++nt) {
                int j = nt * 16 + lr;
                *(unsigned short*)(Pb + m * 256 + (((j >> 3) ^ (m & 7)) << 4) + ((j & 7) << 1)) = f2b(e[nt] * rs);
            }
        }
    }
    __syncthreads();
    // ---- O = P @ V + V, two halves of d
    for (int h = 0; h < 2; ++h) {
        for (int p = 0; p < 8; ++p) {
            int idx = p * 256 + t;
            *(f32x4*)(VTb + idx * 16) = (f32x4){0.f, 0.f, 0.f, 0.f};
        }
        __syncthreads();
        for (int p = 0; p < 7; ++p) {
            int ci = p * 256 + t;
            if (ci < 1600) {
                int j = ci >> 4, d8 = ci & 15;
                s16x8 vv = *(const s16x8*)(QKV + (size_t)(b * 100 + j) * 512 + 256 + h * 128 + d8 * 8);
#pragma unroll
                for (int e = 0; e < 8; ++e) {
                    int dl = d8 * 8 + e;
                    *(unsigned short*)(VTb + dl * 256 + (((j >> 3) ^ (dl & 7)) << 4) + ((j & 7) << 1)) = (unsigned short)vv[e];
                }
            }
        }
        __syncthreads();
        f32x4 O[2][8];
#pragma unroll
        for (int a = 0; a < 2; ++a)
#pragma unroll
            for (int c = 0; c < 8; ++c) O[a][c] = (f32x4){0.f, 0.f, 0.f, 0.f};
#pragma unroll
        for (int kk = 0; kk < 4; ++kk) {
            s16x8 pa[2];
#pragma unroll
            for (int mi = 0; mi < 2; ++mi) {
                int mt = 2 * w + mi;
                if (mt > 6) continue;
                int m = mt * 16 + lr;
                pa[mi] = *(const s16x8*)(Pb + m * 256 + (((kk * 4 + lq) ^ (m & 7)) << 4));
            }
#pragma unroll
            for (int nt = 0; nt < 8; ++nt) {
                int dl = nt * 16 + lr;
                s16x8 vb = *(const s16x8*)(VTb + dl * 256 + (((kk * 4 + lq) ^ (dl & 7)) << 4));
#pragma unroll
                for (int mi = 0; mi < 2; ++mi) {
                    int mt = 2 * w + mi;
                    if (mt > 6) continue;
                    O[mi][nt] = __builtin_amdgcn_mfma_f32_16x16x32_bf16(pa[mi], vb, O[mi][nt], 0, 0, 0);
                }
            }
        }
#pragma unroll
        for (int mi = 0; mi < 2; ++mi) {
            int mt = 2 * w + mi;
            if (mt > 6) continue;
#pragma unroll
            for (int i = 0; i < 4; ++i) {
                int m = mt * 16 + lq * 4 + i;
                if (m < 100) {
#pragma unroll
                    for (int nt = 0; nt < 8; ++nt) {
                        int dl = nt * 16 + lr;
                        float res = b2f(*(unsigned short*)(VTb + dl * 256 + (((m >> 3) ^ (dl & 7)) << 4) + ((m & 7) << 1)));
                        X[(size_t)(b * 100 + m) * 320 + h * 128 + dl] = f2b(O[mi][nt][i] + res);
                    }
                }
            }
        }
        if (h == 0) __syncthreads();
    }
    // ---- time embedding
    for (int p = 0; p < 25; ++p) {
        int idx = p * 256 + t;
        int m = idx >> 6, d = idx & 63;
        float val = intervals[b * 100 + m] * time_w[d] + time_b[d];
        X[(size_t)(b * 100 + m) * 320 + 256 + d] = f2b(val);
    }
}

// ---------------------------------------------------------------- GRU recurrence + classifier.
// Swapped-operand MFMA: C rows = hidden cols j, C cols = batch. Each thread's 4 outputs are
// h[batch][j0..j0+4) -> ONE atomic 8B store publishes them (no drain, no flag, 1-RT sync).
// Readers poll the data (poison 0xFFFF granules); 4-buffer rotation with poison-3-ahead:
//   step s: poll R=buf[s%4] (h_s) -> poison P=buf[(s+3)%4] (held h_{s-1}) -> compute ->
//   store W=buf[(s+1)%4]. Poison ordering: poison (step s) is drained by this wave's step-s+1
//   poll vmcnt(0), which precedes its h_{s+2} publication; readers reach P's read-step (s+3)
//   only after observing h_{s+2}+h_{s+3} => poison is globally visible first. Poison safety:
//   full h_s observed => all plane-w waves finished reading h_{s-1}. Whh slice lives in LDS.
__global__ __launch_bounds__(256, 1) void gru_kernel(const unsigned short* GIb, const unsigned short* WHH,
                                                     const float* gbhh, const int* lens,
                                                     unsigned short* hbA, unsigned short* hbB,
                                                     unsigned short* hbC, unsigned short* hbD,
                                                     const float* clsW, const float* clsb, float* out) {
    __shared__ __align__(16) char Wlds[49152];   // [3 gates][16 j][512 k] bf16, slot-swizzled
    const int bid = blockIdx.x;
    const int t = threadIdx.x, l = t & 63, w = t >> 6;
    const int lo = l & 15, hi = l >> 4, lo7 = l & 7;
    const int batch = w * 16 + lo;          // B-operand col for poll/MFMA
    const int j0 = bid * 16 + hi * 4;       // this thread's 4 output cols (C rows (hi*4+i))
    // stage Whh slice into LDS (once): rows g*16+jl, 64 slots of 16B, slot ^= (jl&7)
    for (int p = 0; p < 12; ++p) {
        int idx = p * 256 + t;              // 16B chunk 0..3071
        int row = idx >> 6, slot = idx & 63;
        int g = row >> 4, jl = row & 15;
        s16x8 v = *(const s16x8*)(WHH + (size_t)(g * 512 + bid * 16 + jl) * 512 + slot * 8);
        *(s16x8*)(Wlds + row * 1024 + ((slot ^ (jl & 7)) << 4)) = v;
    }
    // max length (uniform across blocks)
    int ml;
    {
        int v = lens[l];
        v = max(v, __shfl_xor(v, 1));  v = max(v, __shfl_xor(v, 2));
        v = max(v, __shfl_xor(v, 4));  v = max(v, __shfl_xor(v, 8));
        v = max(v, __shfl_xor(v, 16)); v = max(v, __shfl_xor(v, 32));
        ml = v;
    }
    const int len = lens[batch];
    const f32x4 bhr4 = *(const f32x4*)(gbhh + j0);
    const f32x4 bhz4 = *(const f32x4*)(gbhh + 512 + j0);
    const f32x4 bhn4 = *(const f32x4*)(gbhh + 1024 + j0);
    __syncthreads();

    // per-lane W LDS read bases (A-frag: lane -> W row j_local=lo, k-slice hi*8 + kk*32)
    const int wb0 = (0 * 16 + lo) * 1024;
    const int wb1 = (1 * 16 + lo) * 1024;
    const int wb2 = (2 * 16 + lo) * 1024;

    float ho[4] = {0.f, 0.f, 0.f, 0.f};
    const size_t prow = (size_t)batch * 512 + j0;        // publish/poison slot (8B)
    const size_t arow = (size_t)batch * 512 + hi * 8;    // poll base (16 chunks of 16B, stride 32)
    const size_t gi_row = (size_t)batch * 100;           // GIb row base

    // prefetch gi for step 0 (plain cached loads; GIb read-only)
    s16x4 pgr = *(const s16x4*)(GIb + gi_row * 1536 + j0);
    s16x4 pgz = *(const s16x4*)(GIb + gi_row * 1536 + 512 + j0);
    s16x4 pgn = *(const s16x4*)(GIb + gi_row * 1536 + 1024 + j0);

    unsigned short* R = hbA;   // h_0 = zeros
    unsigned short* W = hbB;   // poison
    unsigned short* X = hbC;   // poison
    unsigned short* P = hbD;   // poison

    for (int step = 0; step < ml; ++step) {
        s16x8 af[16];
        POLL_H(R + arow, af);
        // poison P (held h_{s-1}; every plane-w wave proved done with it by full-h_s observation)
        st_b64_sc(P + prow, 0xFFFFFFFFu, 0xFFFFFFFFu);
        f32x4 ar = (f32x4){0.f,0.f,0.f,0.f}, az = ar, an = ar;
#pragma unroll
        for (int kk = 0; kk < 16; ++kk) {
            const int so = ((kk * 4 + hi) ^ lo7) << 4;
            s16x8 wr = *(const s16x8*)(Wlds + wb0 + so);
            s16x8 wz = *(const s16x8*)(Wlds + wb1 + so);
            s16x8 wn = *(const s16x8*)(Wlds + wb2 + so);
            ar = __builtin_amdgcn_mfma_f32_16x16x32_bf16(wr, af[kk], ar, 0, 0, 0);
            az = __builtin_amdgcn_mfma_f32_16x16x32_bf16(wz, af[kk], az, 0, 0, 0);
            an = __builtin_amdgcn_mfma_f32_16x16x32_bf16(wn, af[kk], an, 0, 0, 0);
        }
        unsigned px, py;
        {
            float h01[2], h23[2];
#pragma unroll
            for (int i = 0; i < 4; ++i) {
                float r = sigm(b2f((unsigned short)pgr[i]) + ar[i] + bhr4[i]);
                float z = sigm(b2f((unsigned short)pgz[i]) + az[i] + bhz4[i]);
                float n = tanhf(b2f((unsigned short)pgn[i]) + r * (an[i] + bhn4[i]));
                float hv = (step < len) ? ((1.f - z) * n + z * ho[i]) : ho[i];
                ho[i] = hv;
                if (i < 2) h01[i] = hv; else h23[i - 2] = hv;
            }
            px = (unsigned)f2b(h01[0]) | ((unsigned)f2b(h01[1]) << 16);
            py = (unsigned)f2b(h23[0]) | ((unsigned)f2b(h23[1]) << 16);
        }
        st_b64_sc(W + prow, px, py);   // single atomic publish; no drain (readers poll data)
        // prefetch next gi (overlaps into next poll)
        if (step + 1 < ml) {
            pgr = *(const s16x4*)(GIb + (gi_row + step + 1) * 1536 + j0);
            pgz = *(const s16x4*)(GIb + (gi_row + step + 1) * 1536 + 512 + j0);
            pgn = *(const s16x4*)(GIb + (gi_row + step + 1) * 1536 + 1024 + j0);
        }
        unsigned short* tmp = R; R = W; W = X; X = P; P = tmp;
    }

    // classifier: 30 blocks x 3 output columns over final h (in R = buf[ml%4]).
    // Wave w's data-poll covers exactly rows [16w,16w+16) = the bb range its classifier
    // threads read; plain reads after are safe (no hb lines in local caches: all hb
    // traffic this dispatch is sc, and dispatch-start acquire invalidated L1/L2).
    if (bid < 30) {
        {
            s16x8 af[16];
            POLL_H(R + arow, af);
        }
        const unsigned short* fbuf = R;
        int bb = t >> 2, qq = t & 3;
        int c0 = bid * 3;
        float s0 = 0.f, s1 = 0.f, s2 = 0.f;
        for (int kc = 0; kc < 16; ++kc) {
            int k = qq * 128 + kc * 8;
            s16x8 hvb = *(const s16x8*)(fbuf + (size_t)bb * 512 + k);
            f32x4 w0a = *(const f32x4*)(clsW + (size_t)(c0 + 0) * 512 + k);
            f32x4 w0b = *(const f32x4*)(clsW + (size_t)(c0 + 0) * 512 + k + 4);
            f32x4 w1a = *(const f32x4*)(clsW + (size_t)(c0 + 1) * 512 + k);
            f32x4 w1b = *(const f32x4*)(clsW + (size_t)(c0 + 1) * 512 + k + 4);
            f32x4 w2a = *(const f32x4*)(clsW + (size_t)(c0 + 2) * 512 + k);
            f32x4 w2b = *(const f32x4*)(clsW + (size_t)(c0 + 2) * 512 + k + 4);
#pragma unroll
            for (int e = 0; e < 4; ++e) {
                float h0 = b2f((unsigned short)hvb[e]);
                float h1 = b2f((unsigned short)hvb[4 + e]);
                s0 += h0 * w0a[e] + h1 * w0b[e];
                s1 += h0 * w1a[e] + h1 * w1b[e];
                s2 += h0 * w2a[e] + h1 * w2b[e];
            }
        }
        s0 += __shfl_xor(s0, 1); s0 += __shfl_xor(s0, 2);
        s1 += __shfl_xor(s1, 1); s1 += __shfl_xor(s1, 2);
        s2 += __shfl_xor(s2, 1); s2 += __shfl_xor(s2, 2);
        if (qq == 0) {
            out[bb * 90 + c0 + 0] = sigm(s0 + clsb[c0 + 0]);
            out[bb * 90 + c0 + 1] = sigm(s1 + clsb[c0 + 1]);
            out[bb * 90 + c0 + 2] = sigm(s2 + clsb[c0 + 2]);
        }
    }
}

// ---------------------------------------------------------------- launch
extern "C" void kernel_launch(void* const* d_in, const int* in_sizes, int n_in,
                              void* d_out, int out_size, void* d_ws, size_t ws_size,
                              hipStream_t stream) {
    const float* code_x   = (const float*)d_in[0];
    const int*   ct0      = (const int*)d_in[1];
    const int*   ct1      = (const int*)d_in[2];
    const int*   ct2      = (const int*)d_in[3];
    const int*   lens     = (const int*)d_in[4];
    const float* intervals= (const float*)d_in[5];
    const float* code_emb = (const float*)d_in[6];
    const float* t0e      = (const float*)d_in[7];
    const float* t1e      = (const float*)d_in[8];
    const float* t2e      = (const float*)d_in[9];
    const float* Wq       = (const float*)d_in[10];
    const float* Wk       = (const float*)d_in[11];
    const float* Wv       = (const float*)d_in[12];
    const float* time_w   = (const float*)d_in[13];
    const float* time_b   = (const float*)d_in[14];
    const float* gWih     = (const float*)d_in[15];
    const float* gWhh     = (const float*)d_in[16];
    const float* gbih     = (const float*)d_in[17];
    const float* gbhh     = (const float*)d_in[18];
    const float* clsW     = (const float*)d_in[19];
    const float* clsb     = (const float*)d_in[20];

    char* ws = (char*)d_ws;
    const size_t ET_OFF   = 0;              // 256*4096*2      = 2,097,152
    const size_t WCAT_OFF = 2097152;        // 512*256*2       =   262,144
    const size_t WIH_OFF  = 2359296;        // 1536*320*2      =   983,040
    const size_t WHH_OFF  = 3342336;        // 1536*512*2      = 1,572,864
    const size_t V_OFF    = 4915200;        // 6400*256*2      = 3,276,800
    const size_t QKV_OFF  = 8192000;        // 6432*512*2      = 6,586,368 (32 pad rows)
    const size_t X_OFF    = 14778368;       // 6400*320*2      = 4,096,000
    const size_t GI_OFF   = 18874368;       // 6400*1536*2     = 19,660,800
    const size_t HB0_OFF  = 38535168;       // 64*512*2        =    65,536
    const size_t HB1_OFF  = 38600704;       // 64*512*2        =    65,536
    const size_t HB2_OFF  = 38666240;       // 64*512*2        =    65,536
    const size_t HB3_OFF  = 38731776;       // 64*512*2        =    65,536

    unsigned short* ET   = (unsigned short*)(ws + ET_OFF);
    unsigned short* WCAT = (unsigned short*)(ws + WCAT_OFF);
    unsigned short* WIH  = (unsigned short*)(ws + WIH_OFF);
    unsigned short* WHH  = (unsigned short*)(ws + WHH_OFF);
    unsigned short* Vb   = (unsigned short*)(ws + V_OFF);
    unsigned short* QKV  = (unsigned short*)(ws + QKV_OFF);
    unsigned short* Xb   = (unsigned short*)(ws + X_OFF);
    unsigned short* GIb  = (unsigned short*)(ws + GI_OFF);
    unsigned short* hb0  = (unsigned short*)(ws + HB0_OFF);
    unsigned short* hb1  = (unsigned short*)(ws + HB1_OFF);
    unsigned short* hb2  = (unsigned short*)(ws + HB2_OFF);
    unsigned short* hb3  = (unsigned short*)(ws + HB3_OFF);

    init_zero<<<8, 256, 0, stream>>>(hb0, hb1, hb2, hb3);
    prep_w<<<512, 256, 0, stream>>>(Wq, Wk, Wv, gWih, gWhh, WCAT, WIH, WHH);
    prep_et<<<dim3(4, 64), 256, 0, stream>>>(code_emb, ct0, ct1, ct2, t0e, t1e, t2e, ET);
    enc_gemm<<<200, 256, 0, stream>>>(code_x, ET, lens, Vb);
    gemm_bf16<<<dim3(200, 2), 256, 0, stream>>>(Vb, WCAT, 256, 512, 2, QKV, nullptr);
    attn_kernel<<<64, 256, 0, stream>>>(QKV, lens, intervals, time_w, time_b, Xb);
    gemm_bf16<<<dim3(200, 6), 256, 0, stream>>>(Xb, WIH, 320, 1536, 1, GIb, gbih);
    gru_kernel<<<32, 256, 0, stream>>>(GIb, WHH, gbhh, lens, hb0, hb1, hb2, hb3, clsW, clsb, (float*)d_out);
}

// Round 6
// 722.923 us; speedup vs baseline: 1.2115x; 1.2115x over previous
//
#include <hip/hip_runtime.h>
#include <hip/hip_bf16.h>

typedef float  f32x4 __attribute__((ext_vector_type(4)));
typedef short  s16x8 __attribute__((ext_vector_type(8)));

#define NEGBIG -1e30f

__device__ __forceinline__ unsigned short f2b(float f) {
    union { float f; unsigned u; } c; c.f = f;
    unsigned r = c.u + 0x7FFF + ((c.u >> 16) & 1);
    return (unsigned short)(r >> 16);
}
__device__ __forceinline__ float b2f(unsigned short h) {
    union { unsigned u; float f; } c; c.u = ((unsigned)h) << 16;
    return c.f;
}
__device__ __forceinline__ float sigm(float x) { return 1.f / (1.f + __expf(-x)); }

// coherent (agent-scope) accessors: bypass per-XCD L1/L2, hit memory-side L3.
__device__ __forceinline__ s16x8 ld_b128_sc(const unsigned short* p) {
    s16x8 r;
    asm volatile("global_load_dwordx4 %0, %1, off sc0 sc1" : "=v"(r) : "v"(p));
    return r;
}
__device__ __forceinline__ void st_short_sc(unsigned short* p, unsigned short v) {
    unsigned int dv = v;
    asm volatile("global_store_short %0, %1, off sc0 sc1" :: "v"(p), "v"(dv) : "memory");
}
__device__ __forceinline__ void st_dword_sc(float* p, float v) {
    asm volatile("global_store_dword %0, %1, off sc0 sc1" :: "v"(p), "v"(v) : "memory");
}

// ---------------------------------------------------------------- fused prep: init + weight casts + E^T build
__global__ __launch_bounds__(256) void prep_all(const float* code_emb, const int* ct0, const int* ct1, const int* ct2,
                                                const float* t0e, const float* t1e, const float* t2e,
                                                const float* Wq, const float* Wk, const float* Wv,
                                                const float* gWih, const float* gWhh,
                                                unsigned short* ET, unsigned short* wcat,
                                                unsigned short* wih, unsigned short* whh,
                                                int* flags, unsigned short* hb0) {
    __shared__ float tile[64][65];
    const int bid = blockIdx.x;
    const int t = threadIdx.x;
    if (bid < 256) {
        // ---- prep_et tile (d0 from low bits, c0 from high bits)
        const int d0 = (bid & 3) * 64, c0 = (bid >> 2) * 64;
        for (int p = 0; p < 16; ++p) {
            int idx = p * 256 + t;
            int dl = idx & 63, cl = idx >> 6;
            int code = c0 + cl + 1;
            int d = d0 + dl;
            float v = code_emb[code * 256 + d] + t0e[ct0[code] * 256 + d]
                    + t1e[ct1[code] * 256 + d] + t2e[ct2[code] * 256 + d];
            tile[dl][cl] = v;
        }
        __syncthreads();
        for (int p = 0; p < 2; ++p) {
            int idx = p * 256 + t;
            int dl = idx >> 3, ch = idx & 7;
            s16x8 pk;
#pragma unroll
            for (int e = 0; e < 8; ++e) pk[e] = (short)f2b(tile[dl][ch * 8 + e]);
            *(s16x8*)(ET + (size_t)(d0 + dl) * 4096 + c0 + ch * 8) = pk;
        }
    } else {
        // ---- init (blocks 504..511) + prep_w grid-stride (blocks 256..511)
        if (bid >= 504) {
            int idx = (bid - 504) * 256 + t;
            for (int i = idx; i < 1024; i += 2048) flags[i] = 0;
            for (int i = idx; i < 32768; i += 2048) hb0[i] = 0;
        }
        int idx = (bid - 256) * 256 + t;
        const int stride = 256 * 256;
        const int N1 = 131072, N2 = 491520, N3 = 786432;
        for (; idx < N1 + N2 + N3; idx += stride) {
            if (idx < N1) {
                int n = idx >> 8, k = idx & 255;
                float v;
                if (n < 128) v = Wq[k * 128 + n];
                else if (n < 256) v = Wk[k * 128 + (n - 128)];
                else v = Wv[k * 256 + (n - 256)];
                wcat[n * 256 + k] = f2b(v);
            } else if (idx < N1 + N2) {
                int i = idx - N1; wih[i] = f2b(gWih[i]);
            } else {
                int i = idx - N1 - N2; whh[i] = f2b(gWhh[i]);
            }
        }
    }
}

// ---------------------------------------------------------------- encoder GEMM: v = mask*( (code_x>0) @ E ) / counts
// 2-deep register prefetch pipeline (static slots A/B; loads for it+2 issued before this iter's MFMA)
__global__ __launch_bounds__(256) void enc_gemm(const float* code_x, const unsigned short* ET,
                                                const int* lens, unsigned short* Vb) {
    __shared__ __align__(16) char sm[4096 + 32768 + 128];
    char* As = sm;
    char* Bs = sm + 4096;
    float* cl = (float*)(sm + 4096 + 32768);
    const int m0 = blockIdx.x * 32;
    const int t = threadIdx.x, l = t & 63, w = t >> 6;
    const int lr = l & 15, lq = l >> 4, l7 = l & 7;
    const int sr = t >> 3, sc = t & 7;
    const int bn = t >> 3, bc = t & 7;
    const float* gabase = code_x + (size_t)(m0 + sr) * 4096 + sc * 8;
    f32x4 acc[2][4];
#pragma unroll
    for (int a = 0; a < 2; ++a)
#pragma unroll
        for (int b = 0; b < 4; ++b) acc[a][b] = (f32x4){0.f, 0.f, 0.f, 0.f};
    int cnt = 0;

    f32x4 a0A, a1A, a0B, a1B;
    s16x8 bA[8], bB[8];

#define ENC_ISSUE(SLOT, IT) do {                                                     \
    const int k0_ = (IT) * 64;                                                       \
    a0##SLOT = *(const f32x4*)(gabase + k0_);                                        \
    a1##SLOT = *(const f32x4*)(gabase + k0_ + 4);                                    \
    _Pragma("unroll")                                                                \
    for (int rd_ = 0; rd_ < 8; ++rd_)                                                \
        b##SLOT[rd_] = *(const s16x8*)(ET + (size_t)(rd_ * 32 + bn) * 4096 + k0_ + bc * 8); \
} while (0)

#define ENC_CONSUME(SLOT, NEXTIT) do {                                               \
    s16x8 ap_;                                                                       \
    _Pragma("unroll")                                                                \
    for (int e_ = 0; e_ < 4; ++e_) { bool on_ = a0##SLOT[e_] > 0.f; ap_[e_] = on_ ? (short)0x3F80 : (short)0; cnt += on_ ? 1 : 0; } \
    _Pragma("unroll")                                                                \
    for (int e_ = 0; e_ < 4; ++e_) { bool on_ = a1##SLOT[e_] > 0.f; ap_[4 + e_] = on_ ? (short)0x3F80 : (short)0; cnt += on_ ? 1 : 0; } \
    *(s16x8*)(As + sr * 128 + ((sc ^ (sr & 7)) << 4)) = ap_;                         \
    _Pragma("unroll")                                                                \
    for (int rd_ = 0; rd_ < 8; ++rd_) {                                              \
        int n_ = rd_ * 32 + bn;                                                      \
        *(s16x8*)(Bs + n_ * 128 + ((bc ^ (n_ & 7)) << 4)) = b##SLOT[rd_];            \
    }                                                                                \
    if ((NEXTIT) < 64) ENC_ISSUE(SLOT, NEXTIT);                                      \
    __syncthreads();                                                                 \
    _Pragma("unroll")                                                                \
    for (int kk_ = 0; kk_ < 2; ++kk_) {                                              \
        const int cp_ = kk_ * 4 + lq;                                                \
        s16x8 af_[2], bf_[4];                                                        \
        _Pragma("unroll")                                                            \
        for (int mt_ = 0; mt_ < 2; ++mt_)                                            \
            af_[mt_] = *(const s16x8*)(As + (mt_ * 16 + lr) * 128 + ((cp_ ^ l7) << 4)); \
        _Pragma("unroll")                                                            \
        for (int nt_ = 0; nt_ < 4; ++nt_)                                            \
            bf_[nt_] = *(const s16x8*)(Bs + ((w * 4 + nt_) * 16 + lr) * 128 + ((cp_ ^ l7) << 4)); \
        _Pragma("unroll")                                                            \
        for (int mt_ = 0; mt_ < 2; ++mt_)                                            \
            _Pragma("unroll")                                                        \
            for (int nt_ = 0; nt_ < 4; ++nt_)                                        \
                acc[mt_][nt_] = __builtin_amdgcn_mfma_f32_16x16x32_bf16(af_[mt_], bf_[nt_], acc[mt_][nt_], 0, 0, 0); \
    }                                                                                \
    __syncthreads();                                                                 \
} while (0)

    ENC_ISSUE(A, 0);
    ENC_ISSUE(B, 1);
    for (int base = 0; base < 64; base += 2) {
        ENC_CONSUME(A, base + 2);
        ENC_CONSUME(B, base + 3);
    }
#undef ENC_ISSUE
#undef ENC_CONSUME

    float fc = (float)cnt;
    fc += __shfl_xor(fc, 1); fc += __shfl_xor(fc, 2); fc += __shfl_xor(fc, 4);
    if (sc == 0) cl[sr] = fmaxf(fc, 1.f);
    __syncthreads();
#pragma unroll
    for (int mt = 0; mt < 2; ++mt)
#pragma unroll
        for (int i = 0; i < 4; ++i) {
            int m = mt * 16 + lq * 4 + i;
            int gm = m0 + m;
            float rc = 1.f / cl[m];
            unsigned bi = (unsigned)gm / 100u;
            unsigned vi = (unsigned)gm - bi * 100u;
            float msk = ((int)vi < lens[bi]) ? 1.f : 0.f;
#pragma unroll
            for (int nt = 0; nt < 4; ++nt) {
                int n = (w * 4 + nt) * 16 + lr;
                Vb[(size_t)gm * 256 + n] = f2b(acc[mt][nt][i] * rc * msk);
            }
        }
}

// ---------------------------------------------------------------- generic bf16 GEMM (A[M][K] @ B[N][K]^T), M tiled by 32, N by 256
// mode 1: out bf16 plain + bias; mode 2: out bf16 plain, no bias. 2-deep register prefetch.
__global__ __launch_bounds__(256) void gemm_bf16(const unsigned short* A, const unsigned short* Bm,
                                                 int K, int Ntot, int mode,
                                                 unsigned short* outp, const float* bias) {
    __shared__ __align__(16) char sm[4096 + 32768];
    char* As = sm;
    char* Bs = sm + 4096;
    const int m0 = blockIdx.x * 32;
    const int n0 = blockIdx.y * 256;
    const int t = threadIdx.x, l = t & 63, w = t >> 6;
    const int lr = l & 15, lq = l >> 4, l7 = l & 7;
    const int sr = t >> 3, sc = t & 7;
    const int bn = t >> 3, bc = t & 7;
    const int iters = K >> 6;
    f32x4 acc[2][4];
#pragma unroll
    for (int a = 0; a < 2; ++a)
#pragma unroll
        for (int b = 0; b < 4; ++b) acc[a][b] = (f32x4){0.f, 0.f, 0.f, 0.f};

    s16x8 avA, avB;
    s16x8 bA[8], bB[8];

#define GB_ISSUE(SLOT, IT) do {                                                      \
    const int k0_ = (IT) * 64;                                                       \
    av##SLOT = *(const s16x8*)(A + (size_t)(m0 + sr) * K + k0_ + sc * 8);            \
    _Pragma("unroll")                                                                \
    for (int rd_ = 0; rd_ < 8; ++rd_)                                                \
        b##SLOT[rd_] = *(const s16x8*)(Bm + (size_t)(n0 + rd_ * 32 + bn) * K + k0_ + bc * 8); \
} while (0)

#define GB_CONSUME(SLOT, NEXTIT) do {                                                \
    *(s16x8*)(As + sr * 128 + ((sc ^ (sr & 7)) << 4)) = av##SLOT;                    \
    _Pragma("unroll")                                                                \
    for (int rd_ = 0; rd_ < 8; ++rd_) {                                              \
        int n_ = rd_ * 32 + bn;                                                      \
        *(s16x8*)(Bs + n_ * 128 + ((bc ^ (n_ & 7)) << 4)) = b##SLOT[rd_];            \
    }                                                                                \
    if ((NEXTIT) < iters) GB_ISSUE(SLOT, NEXTIT);                                    \
    __syncthreads();                                                                 \
    _Pragma("unroll")                                                                \
    for (int kk_ = 0; kk_ < 2; ++kk_) {                                              \
        const int cp_ = kk_ * 4 + lq;                                                \
        s16x8 af_[2], bf_[4];                                                        \
        _Pragma("unroll")                                                            \
        for (int mt_ = 0; mt_ < 2; ++mt_)                                            \
            af_[mt_] = *(const s16x8*)(As + (mt_ * 16 + lr) * 128 + ((cp_ ^ l7) << 4)); \
        _Pragma("unroll")                                                            \
        for (int nt_ = 0; nt_ < 4; ++nt_)                                            \
            bf_[nt_] = *(const s16x8*)(Bs + ((w * 4 + nt_) * 16 + lr) * 128 + ((cp_ ^ l7) << 4)); \
        _Pragma("unroll")                                                            \
        for (int mt_ = 0; mt_ < 2; ++mt_)                                            \
            _Pragma("unroll")                                                        \
            for (int nt_ = 0; nt_ < 4; ++nt_)                                        \
                acc[mt_][nt_] = __builtin_amdgcn_mfma_f32_16x16x32_bf16(af_[mt_], bf_[nt_], acc[mt_][nt_], 0, 0, 0); \
    }                                                                                \
    __syncthreads();                                                                 \
} while (0)

    GB_ISSUE(A, 0);
    if (iters > 1) GB_ISSUE(B, 1);
    for (int base = 0; base < iters; base += 2) {
        GB_CONSUME(A, base + 2);
        if (base + 1 < iters) GB_CONSUME(B, base + 3);
    }
#undef GB_ISSUE
#undef GB_CONSUME

#pragma unroll
    for (int mt = 0; mt < 2; ++mt)
#pragma unroll
        for (int i = 0; i < 4; ++i) {
            int gm = m0 + mt * 16 + lq * 4 + i;
#pragma unroll
            for (int nt = 0; nt < 4; ++nt) {
                int n = n0 + (w * 4 + nt) * 16 + lr;
                float v = acc[mt][nt][i];
                if (mode == 1) v += bias[n];
                outp[(size_t)gm * Ntot + n] = f2b(v);
            }
        }
}

// ---------------------------------------------------------------- attention (block per (batch, d-half)) + time-emb concat
__global__ __launch_bounds__(256) void attn_kernel(const unsigned short* QKV, const int* lens,
                                                   const float* intervals, const float* time_w, const float* time_b,
                                                   unsigned short* X) {
    __shared__ __align__(16) char sm[28672 + 32768];
    char* Pb = sm;            // P: 112 rows x 128 cols bf16, pitch 256B, swizzled
    char* VTb = sm + 28672;   // V^T half: 128 d x 128 j bf16, pitch 256B, swizzled
    const int b = blockIdx.x;
    const int h = blockIdx.y;  // d-half handled by this block
    const int t = threadIdx.x, l = t & 63, w = t >> 6;
    const int lr = l & 15, lq = l >> 4;
    const int lenb = lens[b];
    // zero P
    for (int p = 0; p < 7; ++p) {
        int idx = p * 256 + t;
        *(f32x4*)(Pb + idx * 16) = (f32x4){0.f, 0.f, 0.f, 0.f};
    }
    __syncthreads();
    // ---- S = Q K^T  (rows 2w..2w+1 tiles of 16; wave 3 handles tile 6 only)
    f32x4 S[2][7];
#pragma unroll
    for (int a = 0; a < 2; ++a)
#pragma unroll
        for (int c = 0; c < 7; ++c) S[a][c] = (f32x4){0.f, 0.f, 0.f, 0.f};
#pragma unroll
    for (int kk = 0; kk < 4; ++kk) {
        s16x8 qa[2], kb[7];
#pragma unroll
        for (int mi = 0; mi < 2; ++mi) {
            int mt = 2 * w + mi;
            if (mt > 6) continue;
            int row = b * 100 + mt * 16 + lr;
            qa[mi] = *(const s16x8*)(QKV + (size_t)row * 512 + kk * 32 + lq * 8);
        }
#pragma unroll
        for (int nt = 0; nt < 7; ++nt) {
            int row = b * 100 + nt * 16 + lr;
            kb[nt] = *(const s16x8*)(QKV + (size_t)row * 512 + 128 + kk * 32 + lq * 8);
        }
#pragma unroll
        for (int mi = 0; mi < 2; ++mi) {
            int mt = 2 * w + mi;
            if (mt > 6) continue;
#pragma unroll
            for (int nt = 0; nt < 7; ++nt)
                S[mi][nt] = __builtin_amdgcn_mfma_f32_16x16x32_bf16(qa[mi], kb[nt], S[mi][nt], 0, 0, 0);
        }
    }
    // ---- softmax rows (shuffle groups of 16), store P to LDS
#pragma unroll
    for (int mi = 0; mi < 2; ++mi) {
        int mt = 2 * w + mi;
        if (mt > 6) continue;
        float sv[7][4];
#pragma unroll
        for (int nt = 0; nt < 7; ++nt) {
            int j = nt * 16 + lr;
#pragma unroll
            for (int i = 0; i < 4; ++i)
                sv[nt][i] = (j < lenb) ? S[mi][nt][i] : NEGBIG;
        }
#pragma unroll
        for (int i = 0; i < 4; ++i) {
            float mx = sv[0][i];
#pragma unroll
            for (int nt = 1; nt < 7; ++nt) mx = fmaxf(mx, sv[nt][i]);
            mx = fmaxf(mx, __shfl_xor(mx, 1));
            mx = fmaxf(mx, __shfl_xor(mx, 2));
            mx = fmaxf(mx, __shfl_xor(mx, 4));
            mx = fmaxf(mx, __shfl_xor(mx, 8));
            float e[7], sum = 0.f;
#pragma unroll
            for (int nt = 0; nt < 7; ++nt) { e[nt] = __expf(sv[nt][i] - mx); sum += e[nt]; }
            sum += __shfl_xor(sum, 1);
            sum += __shfl_xor(sum, 2);
            sum += __shfl_xor(sum, 4);
            sum += __shfl_xor(sum, 8);
            float rs = 1.f / sum;
            int m = mt * 16 + lq * 4 + i;
#pragma unroll
            for (int nt = 0; nt < 7; ++nt) {
                int j = nt * 16 + lr;
                *(unsigned short*)(Pb + m * 256 + (((j >> 3) ^ (m & 7)) << 4) + ((j & 7) << 1)) = f2b(e[nt] * rs);
            }
        }
    }
    __syncthreads();
    // ---- O = P @ V + V, this block's d-half only
    for (int p = 0; p < 8; ++p) {
        int idx = p * 256 + t;
        *(f32x4*)(VTb + idx * 16) = (f32x4){0.f, 0.f, 0.f, 0.f};
    }
    __syncthreads();
    for (int p = 0; p < 7; ++p) {
        int ci = p * 256 + t;
        if (ci < 1600) {
            int j = ci >> 4, d8 = ci & 15;
            s16x8 vv = *(const s16x8*)(QKV + (size_t)(b * 100 + j) * 512 + 256 + h * 128 + d8 * 8);
#pragma unroll
            for (int e = 0; e < 8; ++e) {
                int dl = d8 * 8 + e;
                *(unsigned short*)(VTb + dl * 256 + (((j >> 3) ^ (dl & 7)) << 4) + ((j & 7) << 1)) = (unsigned short)vv[e];
            }
        }
    }
    __syncthreads();
    f32x4 O[2][8];
#pragma unroll
    for (int a = 0; a < 2; ++a)
#pragma unroll
        for (int c = 0; c < 8; ++c) O[a][c] = (f32x4){0.f, 0.f, 0.f, 0.f};
#pragma unroll
    for (int kk = 0; kk < 4; ++kk) {
        s16x8 pa[2];
#pragma unroll
        for (int mi = 0; mi < 2; ++mi) {
            int mt = 2 * w + mi;
            if (mt > 6) continue;
            int m = mt * 16 + lr;
            pa[mi] = *(const s16x8*)(Pb + m * 256 + (((kk * 4 + lq) ^ (m & 7)) << 4));
        }
#pragma unroll
        for (int nt = 0; nt < 8; ++nt) {
            int dl = nt * 16 + lr;
            s16x8 vb = *(const s16x8*)(VTb + dl * 256 + (((kk * 4 + lq) ^ (dl & 7)) << 4));
#pragma unroll
            for (int mi = 0; mi < 2; ++mi) {
                int mt = 2 * w + mi;
                if (mt > 6) continue;
                O[mi][nt] = __builtin_amdgcn_mfma_f32_16x16x32_bf16(pa[mi], vb, O[mi][nt], 0, 0, 0);
            }
        }
    }
#pragma unroll
    for (int mi = 0; mi < 2; ++mi) {
        int mt = 2 * w + mi;
        if (mt > 6) continue;
#pragma unroll
        for (int i = 0; i < 4; ++i) {
            int m = mt * 16 + lq * 4 + i;
            if (m < 100) {
#pragma unroll
                for (int nt = 0; nt < 8; ++nt) {
                    int dl = nt * 16 + lr;
                    float res = b2f(*(unsigned short*)(VTb + dl * 256 + (((m >> 3) ^ (dl & 7)) << 4) + ((m & 7) << 1)));
                    X[(size_t)(b * 100 + m) * 320 + h * 128 + dl] = f2b(O[mi][nt][i] + res);
                }
            }
        }
    }
    // ---- time embedding (h==0 block only)
    if (h == 0) {
        for (int p = 0; p < 25; ++p) {
            int idx = p * 256 + t;
            int m = idx >> 6, d = idx & 63;
            float val = intervals[b * 100 + m] * time_w[d] + time_b[d];
            X[(size_t)(b * 100 + m) * 320 + 256 + d] = f2b(val);
        }
    }
}

// ---------------------------------------------------------------- GRU recurrence + classifier (persistent; lightweight
// coherent-data grid barrier: sc0/sc1 accesses bypass per-XCD L1/L2, so no L2 writeback fences are needed)
// EXACT r2 protocol — verified 438 us. (Data-poll variants r3/r5 both regressed: poll-retry traffic
// congests the coherence point. Do not re-attempt without a new mechanism.)
__global__ __launch_bounds__(256, 1) void gru_kernel(const unsigned short* GIb, const unsigned short* WHH,
                                                     const float* gbhh, const int* lens,
                                                     unsigned short* hb0, unsigned short* hb1, float* hf,
                                                     int* flags, const float* clsW, const float* clsb, float* out) {
    const int bid = blockIdx.x;
    const int t = threadIdx.x, l = t & 63, w = t >> 6;
    const int lr = l & 15, lq = l >> 4;
    const int d0 = bid * 16;
    const int j = d0 + lr;
    // max length (uniform)
    int ml;
    {
        int v = lens[l];
        v = max(v, __shfl_xor(v, 1));  v = max(v, __shfl_xor(v, 2));
        v = max(v, __shfl_xor(v, 4));  v = max(v, __shfl_xor(v, 8));
        v = max(v, __shfl_xor(v, 16)); v = max(v, __shfl_xor(v, 32));
        ml = v;
    }
    int lens4[4];
#pragma unroll
    for (int i = 0; i < 4; ++i) lens4[i] = lens[w * 16 + lq * 4 + i];
    const float bhr = gbhh[j], bhz = gbhh[512 + j], bhn = gbhh[1024 + j];
    // Whh fragment slice resident in registers: 3 gates x 16 k-steps (read-only, plain cached loads)
    s16x8 Bf[3][16];
#pragma unroll
    for (int g = 0; g < 3; ++g)
#pragma unroll
        for (int kk = 0; kk < 16; ++kk)
            Bf[g][kk] = *(const s16x8*)(WHH + (size_t)(g * 512 + j) * 512 + kk * 32 + lq * 8);
    float ho[4] = {0.f, 0.f, 0.f, 0.f};
    size_t gi_base[4];
#pragma unroll
    for (int i = 0; i < 4; ++i) gi_base[i] = (size_t)((w * 16 + lq * 4 + i) * 100) * 1536 + j;

    // prefetch gi for step 0 (plain cached loads; GIb is read-only, produced by an earlier dispatch)
    float gir[4], giz[4], gin[4];
#pragma unroll
    for (int i = 0; i < 4; ++i) {
        const unsigned short* gp = GIb + gi_base[i];
        gir[i] = b2f(gp[0]); giz[i] = b2f(gp[512]); gin[i] = b2f(gp[1024]);
    }

    for (int step = 0; step < ml; ++step) {
        const unsigned short* hb = (step & 1) ? hb1 : hb0;
        unsigned short* hn = (step & 1) ? hb0 : hb1;
        // ---- coherent load of h (bypasses stale L1/L2; served by memory-side L3)
        s16x8 af[16];
#pragma unroll
        for (int kk = 0; kk < 16; ++kk)
            af[kk] = ld_b128_sc(hb + (size_t)(w * 16 + lr) * 512 + kk * 32 + lq * 8);
        asm volatile("s_waitcnt vmcnt(0)" ::: "memory");
        __builtin_amdgcn_sched_barrier(0);   // keep MFMAs below the wait (asm loads aren't dep-tracked)
        f32x4 ar = (f32x4){0.f,0.f,0.f,0.f}, az = ar, an = ar;
#pragma unroll
        for (int kk = 0; kk < 16; ++kk) {
            ar = __builtin_amdgcn_mfma_f32_16x16x32_bf16(af[kk], Bf[0][kk], ar, 0, 0, 0);
            az = __builtin_amdgcn_mfma_f32_16x16x32_bf16(af[kk], Bf[1][kk], az, 0, 0, 0);
            an = __builtin_amdgcn_mfma_f32_16x16x32_bf16(af[kk], Bf[2][kk], an, 0, 0, 0);
        }
#pragma unroll
        for (int i = 0; i < 4; ++i) {
            float r = sigm(gir[i] + ar[i] + bhr);
            float z = sigm(giz[i] + az[i] + bhz);
            float n = tanhf(gin[i] + r * (an[i] + bhn));
            float hv = (step < lens4[i]) ? ((1.f - z) * n + z * ho[i]) : ho[i];
            ho[i] = hv;
            st_short_sc(hn + (size_t)(w * 16 + lq * 4 + i) * 512 + j, f2b(hv));
        }
        // ---- publish: drain store-acks (coherence point), arm flag, prefetch next gi, wait
        asm volatile("s_waitcnt vmcnt(0)" ::: "memory");
        __syncthreads();
        if (t == 0)
            __hip_atomic_store(flags + bid * 16, step + 1, __ATOMIC_RELAXED, __HIP_MEMORY_SCOPE_AGENT);
        if (step + 1 < ml) {
#pragma unroll
            for (int i = 0; i < 4; ++i) {
                const unsigned short* gp = GIb + gi_base[i] + (size_t)(step + 1) * 1536;
                gir[i] = b2f(gp[0]); giz[i] = b2f(gp[512]); gin[i] = b2f(gp[1024]);
            }
        }
        if (w == 0) {
            int guard = 0;
            while (true) {
                int v = (l < 32) ? __hip_atomic_load(flags + l * 16, __ATOMIC_RELAXED, __HIP_MEMORY_SCOPE_AGENT) : (step + 1);
                if (__all(v >= step + 1)) break;
                if (++guard > (1 << 20)) break;  // safety: no hang
                __builtin_amdgcn_s_sleep(1);
            }
        }
        __syncthreads();
    }
    // final h (fp32, coherent stores) + classifier
#pragma unroll
    for (int i = 0; i < 4; ++i)
        st_dword_sc(hf + (size_t)(w * 16 + lq * 4 + i) * 512 + j, ho[i]);
    asm volatile("s_waitcnt vmcnt(0)" ::: "memory");
    __syncthreads();
    if (t == 0)
        __hip_atomic_store(flags + bid * 16, ml + 1, __ATOMIC_RELAXED, __HIP_MEMORY_SCOPE_AGENT);
    if (w == 0) {
        int guard = 0;
        while (true) {
            int v = (l < 32) ? __hip_atomic_load(flags + l * 16, __ATOMIC_RELAXED, __HIP_MEMORY_SCOPE_AGENT) : (ml + 1);
            if (__all(v >= ml + 1)) break;
            if (++guard > (1 << 20)) break;
            __builtin_amdgcn_s_sleep(1);
        }
    }
    __syncthreads();
    if (bid < 30) {
        int bb = t >> 2, qq = t & 3;
        int c0 = bid * 3;
        float s0 = 0.f, s1 = 0.f, s2 = 0.f;
        for (int kc = 0; kc < 32; ++kc) {
            int k = qq * 128 + kc * 4;
            f32x4 hv = *(const f32x4*)(hf + bb * 512 + k);
            f32x4 w0 = *(const f32x4*)(clsW + (c0 + 0) * 512 + k);
            f32x4 w1 = *(const f32x4*)(clsW + (c0 + 1) * 512 + k);
            f32x4 w2 = *(const f32x4*)(clsW + (c0 + 2) * 512 + k);
            s0 += hv[0] * w0[0] + hv[1] * w0[1] + hv[2] * w0[2] + hv[3] * w0[3];
            s1 += hv[0] * w1[0] + hv[1] * w1[1] + hv[2] * w1[2] + hv[3] * w1[3];
            s2 += hv[0] * w2[0] + hv[1] * w2[1] + hv[2] * w2[2] + hv[3] * w2[3];
        }
        s0 += __shfl_xor(s0, 1); s0 += __shfl_xor(s0, 2);
        s1 += __shfl_xor(s1, 1); s1 += __shfl_xor(s1, 2);
        s2 += __shfl_xor(s2, 1); s2 += __shfl_xor(s2, 2);
        if (qq == 0) {
            out[bb * 90 + c0 + 0] = sigm(s0 + clsb[c0 + 0]);
            out[bb * 90 + c0 + 1] = sigm(s1 + clsb[c0 + 1]);
            out[bb * 90 + c0 + 2] = sigm(s2 + clsb[c0 + 2]);
        }
    }
}

// ---------------------------------------------------------------- launch
extern "C" void kernel_launch(void* const* d_in, const int* in_sizes, int n_in,
                              void* d_out, int out_size, void* d_ws, size_t ws_size,
                              hipStream_t stream) {
    const float* code_x   = (const float*)d_in[0];
    const int*   ct0      = (const int*)d_in[1];
    const int*   ct1      = (const int*)d_in[2];
    const int*   ct2      = (const int*)d_in[3];
    const int*   lens     = (const int*)d_in[4];
    const float* intervals= (const float*)d_in[5];
    const float* code_emb = (const float*)d_in[6];
    const float* t0e      = (const float*)d_in[7];
    const float* t1e      = (const float*)d_in[8];
    const float* t2e      = (const float*)d_in[9];
    const float* Wq       = (const float*)d_in[10];
    const float* Wk       = (const float*)d_in[11];
    const float* Wv       = (const float*)d_in[12];
    const float* time_w   = (const float*)d_in[13];
    const float* time_b   = (const float*)d_in[14];
    const float* gWih     = (const float*)d_in[15];
    const float* gWhh     = (const float*)d_in[16];
    const float* gbih     = (const float*)d_in[17];
    const float* gbhh     = (const float*)d_in[18];
    const float* clsW     = (const float*)d_in[19];
    const float* clsb     = (const float*)d_in[20];

    char* ws = (char*)d_ws;
    const size_t ET_OFF   = 0;              // 256*4096*2      = 2,097,152
    const size_t WCAT_OFF = 2097152;        // 512*256*2       =   262,144
    const size_t WIH_OFF  = 2359296;        // 1536*320*2      =   983,040
    const size_t WHH_OFF  = 3342336;        // 1536*512*2      = 1,572,864
    const size_t V_OFF    = 4915200;        // 6400*256*2      = 3,276,800
    const size_t QKV_OFF  = 8192000;        // 6432*512*2      = 6,586,368 (32 pad rows)
    const size_t X_OFF    = 14778368;       // 6400*320*2      = 4,096,000
    const size_t GI_OFF   = 18874368;       // 6400*1536*2     = 19,660,800
    const size_t HB0_OFF  = 38535168;       // 64*512*2        =    65,536
    const size_t HB1_OFF  = 38600704;       // 64*512*2        =    65,536
    const size_t HF_OFF   = 38666240;       // 64*512*4        =   131,072
    const size_t FLG_OFF  = 38797312;       // 4096

    unsigned short* ET   = (unsigned short*)(ws + ET_OFF);
    unsigned short* WCAT = (unsigned short*)(ws + WCAT_OFF);
    unsigned short* WIH  = (unsigned short*)(ws + WIH_OFF);
    unsigned short* WHH  = (unsigned short*)(ws + WHH_OFF);
    unsigned short* Vb   = (unsigned short*)(ws + V_OFF);
    unsigned short* QKV  = (unsigned short*)(ws + QKV_OFF);
    unsigned short* Xb   = (unsigned short*)(ws + X_OFF);
    unsigned short* GIb  = (unsigned short*)(ws + GI_OFF);
    unsigned short* hb0  = (unsigned short*)(ws + HB0_OFF);
    unsigned short* hb1  = (unsigned short*)(ws + HB1_OFF);
    float*          hf   = (float*)(ws + HF_OFF);
    int*            flags= (int*)(ws + FLG_OFF);

    prep_all<<<512, 256, 0, stream>>>(code_emb, ct0, ct1, ct2, t0e, t1e, t2e,
                                      Wq, Wk, Wv, gWih, gWhh,
                                      ET, WCAT, WIH, WHH, flags, hb0);
    enc_gemm<<<200, 256, 0, stream>>>(code_x, ET, lens, Vb);
    gemm_bf16<<<dim3(200, 2), 256, 0, stream>>>(Vb, WCAT, 256, 512, 2, QKV, nullptr);
    attn_kernel<<<dim3(64, 2), 256, 0, stream>>>(QKV, lens, intervals, time_w, time_b, Xb);
    gemm_bf16<<<dim3(200, 6), 256, 0, stream>>>(Xb, WIH, 320, 1536, 1, GIb, gbih);
    gru_kernel<<<32, 256, 0, stream>>>(GIb, WHH, gbhh, lens, hb0, hb1, hf, flags, clsW, clsb, (float*)d_out);
}